// Round 12
// baseline (310.014 us; speedup 1.0000x reference)
//
#include <hip/hip_runtime.h>

#define D 256
#define ROWS 32
#define NBLK 256

typedef __attribute__((ext_vector_type(8))) short bf16x8;
typedef __attribute__((ext_vector_type(4))) float f32x4;

__device__ __forceinline__ unsigned short f2bf(float a) {
    unsigned int u = __float_as_uint(a);
    u = (u + 0x7fffu + ((u >> 16) & 1u)) >> 16;
    return (unsigned short)u;
}

__device__ __forceinline__ unsigned int cvt_pk_bf16(float a, float b) {
    unsigned int r;
    asm("v_cvt_pk_bf16_f32 %0, %1, %2" : "=v"(r) : "v"(a), "v"(b));
    return r;
}

__device__ __forceinline__ float fast_tanh(float v) {
    float a = __builtin_fabsf(v);
    float e = __builtin_amdgcn_exp2f(a * -2.88539008177793f);   // exp(-2a)
    float t = (1.0f - e) * __builtin_amdgcn_rcpf(1.0f + e);
    return __builtin_copysignf(t, v);
}

// Swizzled byte offset into the f32 x-tile (k-major transposed):
// chunk c = col8 (0..31), row r (0..31), 16B-half q (0..1).
__device__ __forceinline__ int xf_off(int c, int r, int q) {
    return ((c << 10) + (r << 5) + (q << 4)) ^ ((c & 3) << 5) ^ ((r & 4) << 2);
}

__device__ __forceinline__ void gload_lds16(const void* g, void* l) {
    __builtin_amdgcn_global_load_lds(
        (const __attribute__((address_space(1))) unsigned int*)g,
        (__attribute__((address_space(3))) unsigned int*)l, 16, 0, 0);
}

// ---------------------------------------------------------------------------
__global__ void pack_w1_k(const float* __restrict__ W1, unsigned short* __restrict__ W1p) {
    int p = blockIdx.x * 256 + threadIdx.x;   // 0 .. 65535
    int e  = p & 7;
    int l  = (p >> 3) & 63;
    int cb = (p >> 9) & 15;
    int kk = p >> 13;
    int k   = 32 * kk + 8 * (l >> 4) + e;
    int col = 16 * cb + (l & 15);
    W1p[p] = f2bf(W1[k * D + col]);
}

__global__ void zero_k(float* __restrict__ p, int n) {
    int i = blockIdx.x * 256 + threadIdx.x;
    if (i < n) p[i] = 0.f;
}

// ---------------------------------------------------------------------------
// STAGE: async global->LDS of one 32x256 f32 tile (1024 threads: 2 iters),
// linear LDS dest, inverse-swizzled per-lane global source.
#define STAGE(XN, tn) do {                                                      \
    const int _r0s = (tn) * ROWS;                                               \
    _Pragma("unroll")                                                           \
    for (int _it = 0; _it < 2; ++_it) {                                         \
        const int _c = _it * 16 + w;                                            \
        const int _r = (l >> 1) ^ (_c & 3);                                     \
        const int _q = (l & 1) ^ ((_r >> 2) & 1);                               \
        int _row = _r0s + _r; _row = (_row < N) ? _row : (N - 1);               \
        gload_lds16((const char*)x + ((size_t)_row << 10) + (size_t)(((_c << 1) + _q) << 4), \
                    (char*)(XN) + (_it << 14) + (w << 10) + (l << 4));          \
    }                                                                           \
} while (0)

// FLUSHX: emit accumulated (a4, den_p) for g_cur; compute next graph id -> gnv.
#define FLUSHX() do {                                                           \
    *reinterpret_cast<float4*>(&red[w][l * 4]) = a4;                            \
    int _m8 = 0x7fffffff;                                                       \
    _Pragma("unroll")                                                           \
    for (int _it = 0; _it < 2; ++_it)                                           \
        if (bg[_it] > g_cur && bg[_it] < _m8) _m8 = bg[_it];                    \
    _m8 = min(_m8, __shfl_xor(_m8, 1));  _m8 = min(_m8, __shfl_xor(_m8, 2));    \
    _m8 = min(_m8, __shfl_xor(_m8, 4));  _m8 = min(_m8, __shfl_xor(_m8, 8));    \
    _m8 = min(_m8, __shfl_xor(_m8, 16)); _m8 = min(_m8, __shfl_xor(_m8, 32));   \
    float _dw = den_p;                                                          \
    _dw += __shfl_xor(_dw, 1);  _dw += __shfl_xor(_dw, 2);                      \
    _dw += __shfl_xor(_dw, 4);  _dw += __shfl_xor(_dw, 8);                      \
    _dw += __shfl_xor(_dw, 16); _dw += __shfl_xor(_dw, 32);                     \
    if (l == 0) { gmin16[w] = _m8; denw[w] = _dw; }                             \
    asm volatile("s_waitcnt lgkmcnt(0)" ::: "memory");                          \
    __builtin_amdgcn_sched_barrier(0);                                          \
    __builtin_amdgcn_s_barrier();                                               \
    __builtin_amdgcn_sched_barrier(0);                                          \
    if (tid < 256) {                                                            \
        float _fs = 0.f;                                                        \
        _Pragma("unroll")                                                       \
        for (int _j = 0; _j < 16; ++_j) _fs += red[_j][tid];                    \
        atomicAdd(&accb[(size_t)g_cur * D + tid], _fs);                         \
    }                                                                           \
    if (tid == 0) {                                                             \
        float _ds = 0.f;                                                        \
        _Pragma("unroll")                                                       \
        for (int _j = 0; _j < 16; ++_j) _ds += denw[_j];                        \
        atomicAdd(&den[g_cur], _ds * 0.015625f);                                \
    }                                                                           \
    gnv = 0x7fffffff;                                                           \
    _Pragma("unroll")                                                           \
    for (int _j = 0; _j < 16; ++_j) gnv = min(gnv, gmin16[_j]);                 \
    a4 = make_float4(0.f, 0.f, 0.f, 0.f); den_p = 0.f;                          \
    __builtin_amdgcn_s_barrier();                                               \
    __builtin_amdgcn_sched_barrier(0);                                          \
} while (0)

// POOL: wave w accumulates rows {w, w+16} into (a4, den_p); flush on change.
// Each row covered by its wave's 64 lanes -> den scaled 1/64 at flush.
#define POOL(XC) do {                                                           \
    if (g_cur < 0) g_cur = g0u;                                                 \
    while (true) {                                                              \
        _Pragma("unroll")                                                       \
        for (int _it = 0; _it < 2; ++_it) {                                     \
            const int _r = w + 16 * _it;                                        \
            const float _e = (bg[_it] == g_cur) ? erow[_r] : 0.f;               \
            const float4 _v = *reinterpret_cast<const float4*>(                 \
                (const char*)(XC) + xf_off(l >> 1, _r, l & 1));                 \
            a4.x += _e * _v.x; a4.y += _e * _v.y;                               \
            a4.z += _e * _v.z; a4.w += _e * _v.w;                               \
            den_p += _e;                                                        \
        }                                                                       \
        if (glast <= g_cur) break;                                              \
        FLUSHX();                                                               \
        g_cur = gnv;                                                            \
    }                                                                           \
} while (0)

// BODY: process tile t from XC, prefetch tile t+1 into XN. ++t at end.
// Identical chain to R5 (zero-VMEM kk-loop; async dbuf stage; counted vmcnt),
// re-tiled for 16 waves: wave = (rg = w>>3 row-group) x (cg = w&7 col-group).
#define BODY(XC, XN) do {                                                       \
    const int _row0 = t * ROWS;                                                 \
    _Pragma("unroll")                                                           \
    for (int _it = 0; _it < 2; ++_it) {                                         \
        int _ri = _row0 + w + 16 * _it;                                         \
        bg[_it] = batch[_ri < N ? _ri : N - 1];                                 \
    }                                                                           \
    const int g0u = batch[_row0];                                               \
    int _gli = _row0 + 31;                                                      \
    const int glast = batch[_gli < N ? _gli : N - 1];                           \
    __builtin_amdgcn_sched_barrier(0);                                          \
    const bool _hn = (t + 1 < t1);                                              \
    if (_hn) {                                                                  \
        STAGE(XN, t + 1);                                                       \
        asm volatile("s_waitcnt vmcnt(4) lgkmcnt(0)" ::: "memory");             \
    } else {                                                                    \
        asm volatile("s_waitcnt vmcnt(0) lgkmcnt(0)" ::: "memory");             \
    }                                                                           \
    __builtin_amdgcn_sched_barrier(0);                                          \
    __builtin_amdgcn_s_barrier();                                               \
    __builtin_amdgcn_sched_barrier(0);                                          \
    /* ---- scores: wave (rg,cg) computes rows 16rg..16rg+16 x cols 32cg.. ---- */ \
    f32x4 acc0 = (f32x4){0.f, 0.f, 0.f, 0.f};                                   \
    f32x4 acc1 = (f32x4){0.f, 0.f, 0.f, 0.f};                                   \
    _Pragma("unroll")                                                           \
    for (int _kk = 0; _kk < 8; ++_kk) {                                         \
        const int _rr = 16 * rg + l15;                                          \
        const int _cc = 4 * _kk + g4;                                           \
        const int _o0 = xf_off(_cc, _rr, 0);                                    \
        const float4 _f0 = *reinterpret_cast<const float4*>((const char*)(XC) + _o0); \
        const float4 _f1 = *reinterpret_cast<const float4*>((const char*)(XC) + (_o0 ^ 16)); \
        uint4 _u;                                                               \
        _u.x = cvt_pk_bf16(_f0.x, _f0.y); _u.y = cvt_pk_bf16(_f0.z, _f0.w);     \
        _u.z = cvt_pk_bf16(_f1.x, _f1.y); _u.w = cvt_pk_bf16(_f1.z, _f1.w);     \
        const bf16x8 _afr = *reinterpret_cast<bf16x8*>(&_u);                    \
        acc0 = __builtin_amdgcn_mfma_f32_16x16x32_bf16(_afr, bfr[_kk * 2 + 0], acc0, 0, 0, 0); \
        acc1 = __builtin_amdgcn_mfma_f32_16x16x32_bf16(_afr, bfr[_kk * 2 + 1], acc1, 0, 0, 0); \
    }                                                                           \
    /* ---- epilogue: +b1, tanh, *W2, 16-lane reduce -> scpart[cg][row] ---- */ \
    _Pragma("unroll")                                                           \
    for (int _r = 0; _r < 4; ++_r) {                                            \
        float _p = fast_tanh(acc0[_r] + b1v0) * w2v0                            \
                 + fast_tanh(acc1[_r] + b1v1) * w2v1;                           \
        _p += __shfl_xor(_p, 8, 16); _p += __shfl_xor(_p, 4, 16);               \
        _p += __shfl_xor(_p, 2, 16); _p += __shfl_xor(_p, 1, 16);               \
        if (l15 == 0) scpart[cg][16 * rg + 4 * g4 + _r] = _p;                   \
    }                                                                           \
    asm volatile("s_waitcnt lgkmcnt(0)" ::: "memory");                          \
    __builtin_amdgcn_sched_barrier(0);                                          \
    __builtin_amdgcn_s_barrier();                                               \
    __builtin_amdgcn_sched_barrier(0);                                          \
    if (tid < 32) {                                                             \
        float _s = 0.f;                                                         \
        _Pragma("unroll")                                                       \
        for (int _j = 0; _j < 8; ++_j) _s += scpart[_j][tid];                   \
        erow[tid] = ((_row0 + tid) < N)                                         \
                  ? __builtin_amdgcn_exp2f(_s * 1.4426950408889634f) : 0.f;     \
    }                                                                           \
    asm volatile("s_waitcnt lgkmcnt(0)" ::: "memory");                          \
    __builtin_amdgcn_sched_barrier(0);                                          \
    __builtin_amdgcn_s_barrier();                                               \
    __builtin_amdgcn_sched_barrier(0);                                          \
    POOL(XC);                                                                   \
    asm volatile("s_waitcnt lgkmcnt(0)" ::: "memory");                          \
    __builtin_amdgcn_sched_barrier(0);                                          \
    __builtin_amdgcn_s_barrier();                                               \
    __builtin_amdgcn_sched_barrier(0);                                          \
    ++t;                                                                        \
} while (0)

// ---------------------------------------------------------------------------
// Persistent fused kernel, ONE 1024-thread block per CU (16 waves = 4/SIMD).
// Same invariants as R5 (best, 189 us): zero-VMEM kk-loop (W1p cached in
// regs -- now 64 VGPR/wave since each wave owns 32 cols), async dbuf
// gload_lds staging with counted vmcnt, exact-f32 LDS pooling. 2x the
// co-resident waves of R5 at identical aggregate LDS/HBM/MFMA work.
// ---------------------------------------------------------------------------
__global__ void __launch_bounds__(1024)
fused_k(const float* __restrict__ x,
        const unsigned short* __restrict__ W1p,
        const float* __restrict__ b1,
        const float* __restrict__ W2,
        const float* __restrict__ b2,
        const int* __restrict__ batch,
        int N, int NT,
        float* __restrict__ accb, float* __restrict__ den) {
    __shared__ __align__(16) char Xf0[32768];
    __shared__ __align__(16) char Xf1[32768];
    __shared__ __align__(16) float red[16][256];
    __shared__ float scpart[8][32];
    __shared__ float erow[32];
    __shared__ int   gmin16[16];
    __shared__ float denw[16];

    const int tid = threadIdx.x;
    const int w   = tid >> 6;       // wave 0..15
    const int l   = tid & 63;
    const int l15 = l & 15;
    const int g4  = l >> 4;
    const int rg  = w >> 3;         // row group 0..1 (rows 16rg..16rg+15)
    const int cg  = w & 7;          // col group 0..7 (cols 32cg..32cg+31)

    const int tpb = (NT + NBLK - 1) / NBLK;
    int t = blockIdx.x * tpb;
    const int t1 = min(NT, t + tpb);
    if (t >= t1) return;

    // cache this wave's W1p slice (cols 32cg..32cg+31): 16 x bf16x8 = 64 VGPR
    bf16x8 bfr[16];
    #pragma unroll
    for (int kk = 0; kk < 8; ++kk)
        #pragma unroll
        for (int n = 0; n < 2; ++n)
            bfr[kk * 2 + n] = *reinterpret_cast<const bf16x8*>(
                W1p + (size_t)(((kk * 16) + (cg * 2 + n)) * 64 + l) * 8);

    const float b1v0 = b1[32 * cg + l15];
    const float b1v1 = b1[32 * cg + 16 + l15];
    const float w2v0 = W2[32 * cg + l15];
    const float w2v1 = W2[32 * cg + 16 + l15];

    // prologue: stage first tile into Xf0
    STAGE(Xf0, t);

    float4 a4 = make_float4(0.f, 0.f, 0.f, 0.f);
    float den_p = 0.f;
    int g_cur = -1;
    int gnv = 0;
    int bg[2];   // kernel scope: final FLUSHX uses last body's values

    while (true) {
        BODY(Xf0, Xf1);
        if (t >= t1) break;
        BODY(Xf1, Xf0);
        if (t >= t1) break;
    }

    // final flush of the last graph
    FLUSHX();
}

// ---------------------------------------------------------------------------
__global__ void __launch_bounds__(256)
norm_k(const float* __restrict__ accb, const float* __restrict__ den,
       float* __restrict__ out) {
    int g = blockIdx.x;
    float dv = den[g];
    float inv = (dv > 0.f) ? 1.0f / dv : 0.f;
    out[(size_t)g * D + threadIdx.x] = accb[(size_t)g * D + threadIdx.x] * inv;
}

// ---------------------------------------------------------------------------
extern "C" void kernel_launch(void* const* d_in, const int* in_sizes, int n_in,
                              void* d_out, int out_size, void* d_ws, size_t ws_size,
                              hipStream_t stream) {
    const float* x     = (const float*)d_in[0];
    const int*   batch = (const int*)d_in[1];
    const float* W1    = (const float*)d_in[3];
    const float* b1    = (const float*)d_in[4];
    const float* W2    = (const float*)d_in[5];
    const float* b2    = (const float*)d_in[6];
    float* out = (float*)d_out;
    (void)b2;   // b2 cancels in attn = e/(sum e); verified r11 (absmax unchanged)

    const int N = in_sizes[0] / D;
    const int G = out_size / D;
    const int NT = (N + ROWS - 1) / ROWS;

    char* ws = (char*)d_ws;
    unsigned short* W1p = (unsigned short*)ws;               // 128 KB
    float* accb = (float*)(ws + 131072);                     // G*D*4 bytes
    float* den  = (float*)(ws + 131072 + (size_t)G * D * 4); // G*4, contiguous

    zero_k<<<dim3((G * D + G + 255) / 256), dim3(256), 0, stream>>>(accb, G * D + G);
    pack_w1_k<<<dim3(256), dim3(256), 0, stream>>>(W1, W1p);
    fused_k<<<dim3(min(NBLK, NT)), dim3(1024), 0, stream>>>(x, W1p, b1, W2, b2, batch,
                                                            N, NT, accb, den);
    norm_k<<<dim3(G), dim3(256), 0, stream>>>(accb, den, out);
}

// Round 13
// 198.504 us; speedup vs baseline: 1.5618x; 1.5618x over previous
//
#include <hip/hip_runtime.h>

#define D 256
#define ROWS 32
#define NBLK 512

typedef __attribute__((ext_vector_type(8))) short bf16x8;
typedef __attribute__((ext_vector_type(4))) float f32x4;

__device__ __forceinline__ unsigned short f2bf(float a) {
    unsigned int u = __float_as_uint(a);
    u = (u + 0x7fffu + ((u >> 16) & 1u)) >> 16;
    return (unsigned short)u;
}

__device__ __forceinline__ unsigned int cvt_pk_bf16(float a, float b) {
    unsigned int r;
    asm("v_cvt_pk_bf16_f32 %0, %1, %2" : "=v"(r) : "v"(a), "v"(b));
    return r;
}

__device__ __forceinline__ float fast_tanh(float v) {
    float a = __builtin_fabsf(v);
    float e = __builtin_amdgcn_exp2f(a * -2.88539008177793f);   // exp(-2a)
    float t = (1.0f - e) * __builtin_amdgcn_rcpf(1.0f + e);
    return __builtin_copysignf(t, v);
}

// Swizzled byte offset into the f32 x-tile (k-major transposed):
// chunk c = col8 (0..31), row r (0..31), 16B-half q (0..1).
__device__ __forceinline__ int xf_off(int c, int r, int q) {
    return ((c << 10) + (r << 5) + (q << 4)) ^ ((c & 3) << 5) ^ ((r & 4) << 2);
}

__device__ __forceinline__ void gload_lds16(const void* g, void* l) {
    __builtin_amdgcn_global_load_lds(
        (const __attribute__((address_space(1))) unsigned int*)g,
        (__attribute__((address_space(3))) unsigned int*)l, 16, 0, 0);
}

// ---------------------------------------------------------------------------
__global__ void pack_w1_k(const float* __restrict__ W1, unsigned short* __restrict__ W1p) {
    int p = blockIdx.x * 256 + threadIdx.x;   // 0 .. 65535
    int e  = p & 7;
    int l  = (p >> 3) & 63;
    int cb = (p >> 9) & 15;
    int kk = p >> 13;
    int k   = 32 * kk + 8 * (l >> 4) + e;
    int col = 16 * cb + (l & 15);
    W1p[p] = f2bf(W1[k * D + col]);
}

__global__ void zero_k(float* __restrict__ p, int n) {
    int i = blockIdx.x * 256 + threadIdx.x;
    if (i < n) p[i] = 0.f;
}

// ---------------------------------------------------------------------------
// STAGE: async global->LDS of one 32x256 f32 tile, linear LDS dest,
// inverse-swizzled per-lane global source (so swizzled reads see x[r][8c..]).
#define STAGE(XN, tn) do {                                                      \
    const int _r0s = (tn) * ROWS;                                               \
    _Pragma("unroll")                                                           \
    for (int _it = 0; _it < 8; ++_it) {                                         \
        const int _c = _it * 4 + w;                                             \
        const int _r = (l >> 1) ^ (_c & 3);                                     \
        const int _q = (l & 1) ^ ((_r >> 2) & 1);                               \
        int _row = _r0s + _r; _row = (_row < N) ? _row : (N - 1);               \
        gload_lds16((const char*)x + ((size_t)_row << 10) + (size_t)(((_c << 1) + _q) << 4), \
                    (char*)(XN) + (_it << 12) + (w << 10) + (l << 4));          \
    }                                                                           \
} while (0)

// FLUSHX: emit accumulated (a4, den_p) for g_cur; compute next graph id -> gnv.
#define FLUSHX() do {                                                           \
    *reinterpret_cast<float4*>(&red[w][l * 4]) = a4;                            \
    int _m8 = 0x7fffffff;                                                       \
    _Pragma("unroll")                                                           \
    for (int _it = 0; _it < 8; ++_it)                                           \
        if (bg[_it] > g_cur && bg[_it] < _m8) _m8 = bg[_it];                    \
    _m8 = min(_m8, __shfl_xor(_m8, 1));  _m8 = min(_m8, __shfl_xor(_m8, 2));    \
    _m8 = min(_m8, __shfl_xor(_m8, 4));  _m8 = min(_m8, __shfl_xor(_m8, 8));    \
    _m8 = min(_m8, __shfl_xor(_m8, 16)); _m8 = min(_m8, __shfl_xor(_m8, 32));   \
    float _dw = den_p;                                                          \
    _dw += __shfl_xor(_dw, 1);  _dw += __shfl_xor(_dw, 2);                      \
    _dw += __shfl_xor(_dw, 4);  _dw += __shfl_xor(_dw, 8);                      \
    _dw += __shfl_xor(_dw, 16); _dw += __shfl_xor(_dw, 32);                     \
    if (l == 0) { gmin4[w] = _m8; denw[w] = _dw; }                              \
    asm volatile("s_waitcnt lgkmcnt(0)" ::: "memory");                          \
    __builtin_amdgcn_sched_barrier(0);                                          \
    __builtin_amdgcn_s_barrier();                                               \
    __builtin_amdgcn_sched_barrier(0);                                          \
    { const float _fs = red[0][tid] + red[1][tid] + red[2][tid] + red[3][tid];  \
      atomicAdd(&accb[(size_t)g_cur * D + tid], _fs); }                         \
    if (tid == 0)                                                               \
        atomicAdd(&den[g_cur], (denw[0] + denw[1] + denw[2] + denw[3]) * 0.015625f); \
    gnv = min(min(gmin4[0], gmin4[1]), min(gmin4[2], gmin4[3]));                \
    a4 = make_float4(0.f, 0.f, 0.f, 0.f); den_p = 0.f;                          \
    __builtin_amdgcn_s_barrier();                                               \
    __builtin_amdgcn_sched_barrier(0);                                          \
} while (0)

// POOL: accumulate this tile's rows into (a4, den_p) using the register-
// resident _ev[] (per-row exp), flushing on graph change. Row r handled by
// all 64 lanes of wave r%4 -> den scaled by 1/64 at flush.
#define POOL(XC) do {                                                           \
    if (g_cur < 0) g_cur = g0u;                                                 \
    while (true) {                                                              \
        _Pragma("unroll")                                                       \
        for (int _it = 0; _it < 8; ++_it) {                                     \
            const int _r = 4 * _it + w;                                         \
            const float _e = (bg[_it] == g_cur) ? _ev[_it] : 0.f;               \
            const float4 _v = *reinterpret_cast<const float4*>(                 \
                (const char*)(XC) + xf_off(l >> 1, _r, l & 1));                 \
            a4.x += _e * _v.x; a4.y += _e * _v.y;                               \
            a4.z += _e * _v.z; a4.w += _e * _v.w;                               \
            den_p += _e;                                                        \
        }                                                                       \
        if (glast <= g_cur) break;                                              \
        FLUSHX();                                                               \
        g_cur = gnv;                                                            \
    }                                                                           \
} while (0)

// BODY: process tile t from XC, prefetch tile t+1 into XN. ++t at end.
// vs R5: the 32-thread erow phase and its barrier trio are DELETED -- every
// thread redundantly reduces its own 8 pool rows from scpart into _ev[8]
// (all lanes busy; one fewer block-wide barrier). No setprio (m190).
#define BODY(XC, XN) do {                                                       \
    const int _row0 = t * ROWS;                                                 \
    _Pragma("unroll")                                                           \
    for (int _it = 0; _it < 8; ++_it) {                                         \
        int _ri = _row0 + 4 * _it + w;                                          \
        bg[_it] = batch[_ri < N ? _ri : N - 1];                                 \
    }                                                                           \
    const int g0u = batch[_row0];                                               \
    int _gli = _row0 + 31;                                                      \
    const int glast = batch[_gli < N ? _gli : N - 1];                           \
    __builtin_amdgcn_sched_barrier(0);                                          \
    const bool _hn = (t + 1 < t1);                                              \
    if (_hn) {                                                                  \
        STAGE(XN, t + 1);                                                       \
        asm volatile("s_waitcnt vmcnt(8) lgkmcnt(0)" ::: "memory");             \
    } else {                                                                    \
        asm volatile("s_waitcnt vmcnt(0) lgkmcnt(0)" ::: "memory");             \
    }                                                                           \
    __builtin_amdgcn_sched_barrier(0);                                          \
    __builtin_amdgcn_s_barrier();                                               \
    __builtin_amdgcn_sched_barrier(0);                                          \
    /* ---- scores: tanh(x@W1+b1)@W2 ; A from XC (f32+cvt), B from regs ---- */ \
    f32x4 acc[2][4];                                                            \
    _Pragma("unroll")                                                           \
    for (int _m = 0; _m < 2; ++_m)                                              \
        _Pragma("unroll")                                                       \
        for (int _n = 0; _n < 4; ++_n) acc[_m][_n] = (f32x4){0.f, 0.f, 0.f, 0.f}; \
    _Pragma("unroll")                                                           \
    for (int _kk = 0; _kk < 8; ++_kk) {                                         \
        bf16x8 _afr[2];                                                         \
        _Pragma("unroll")                                                       \
        for (int _m = 0; _m < 2; ++_m) {                                        \
            const int _rr = 16 * _m + l15;                                      \
            const int _cc = 4 * _kk + g4;                                       \
            const int _o0 = xf_off(_cc, _rr, 0);                                \
            const float4 _f0 = *reinterpret_cast<const float4*>((const char*)(XC) + _o0); \
            const float4 _f1 = *reinterpret_cast<const float4*>((const char*)(XC) + (_o0 ^ 16)); \
            uint4 _u;                                                           \
            _u.x = cvt_pk_bf16(_f0.x, _f0.y); _u.y = cvt_pk_bf16(_f0.z, _f0.w); \
            _u.z = cvt_pk_bf16(_f1.x, _f1.y); _u.w = cvt_pk_bf16(_f1.z, _f1.w); \
            _afr[_m] = *reinterpret_cast<bf16x8*>(&_u);                         \
        }                                                                       \
        _Pragma("unroll")                                                       \
        for (int _m = 0; _m < 2; ++_m)                                          \
            _Pragma("unroll")                                                   \
            for (int _n = 0; _n < 4; ++_n)                                      \
                acc[_m][_n] = __builtin_amdgcn_mfma_f32_16x16x32_bf16(          \
                    _afr[_m], bfr[_kk * 4 + _n], acc[_m][_n], 0, 0, 0);         \
    }                                                                           \
    {                                                                           \
        float _part[2][4];                                                      \
        _Pragma("unroll")                                                       \
        for (int _m = 0; _m < 2; ++_m)                                          \
            _Pragma("unroll")                                                   \
            for (int _r = 0; _r < 4; ++_r) _part[_m][_r] = 0.f;                 \
        _Pragma("unroll")                                                       \
        for (int _n = 0; _n < 4; ++_n)                                          \
            _Pragma("unroll")                                                   \
            for (int _m = 0; _m < 2; ++_m)                                      \
                _Pragma("unroll")                                               \
                for (int _r = 0; _r < 4; ++_r) {                                \
                    float _h = fast_tanh(acc[_m][_n][_r] + b1v[_n]);            \
                    _part[_m][_r] += _h * w2v[_n];                              \
                }                                                               \
        _Pragma("unroll")                                                       \
        for (int _m = 0; _m < 2; ++_m)                                          \
            _Pragma("unroll")                                                   \
            for (int _r = 0; _r < 4; ++_r) {                                    \
                float _p = _part[_m][_r];                                       \
                _p += __shfl_xor(_p, 8, 16); _p += __shfl_xor(_p, 4, 16);       \
                _p += __shfl_xor(_p, 2, 16); _p += __shfl_xor(_p, 1, 16);       \
                if (l15 == 0) scpart[w][16 * _m + 4 * g4 + _r] = _p;            \
            }                                                                   \
    }                                                                           \
    asm volatile("s_waitcnt lgkmcnt(0)" ::: "memory");                          \
    __builtin_amdgcn_sched_barrier(0);                                          \
    __builtin_amdgcn_s_barrier();                                               \
    __builtin_amdgcn_sched_barrier(0);                                          \
    /* ---- pool prep: per-thread redundant row-sum + exp (b2 cancels) ---- */  \
    float _ev[8];                                                               \
    _Pragma("unroll")                                                           \
    for (int _it = 0; _it < 8; ++_it) {                                         \
        const int _r = 4 * _it + w;                                             \
        const float _s = scpart[0][_r] + scpart[1][_r]                          \
                       + scpart[2][_r] + scpart[3][_r];                         \
        _ev[_it] = (_row0 + _r < N)                                             \
                 ? __builtin_amdgcn_exp2f(_s * 1.4426950408889634f) : 0.f;      \
    }                                                                           \
    POOL(XC);                                                                   \
    asm volatile("s_waitcnt lgkmcnt(0)" ::: "memory");                          \
    __builtin_amdgcn_sched_barrier(0);                                          \
    __builtin_amdgcn_s_barrier();                                               \
    __builtin_amdgcn_sched_barrier(0);                                          \
    ++t;                                                                        \
} while (0)

// ---------------------------------------------------------------------------
// Persistent fused kernel: R5 structure verbatim (async gload_lds dbuf
// staging, W1p quarter cached in 128 VGPRs, exact-f32 LDS pooling, 2 blocks
// per CU) with ONE change: erow serial phase + one barrier trio replaced by
// per-thread redundant scpart reduction into registers.
// ---------------------------------------------------------------------------
__global__ void __launch_bounds__(256, 2)
fused_k(const float* __restrict__ x,
        const unsigned short* __restrict__ W1p,
        const float* __restrict__ b1,
        const float* __restrict__ W2,
        const float* __restrict__ b2,
        const int* __restrict__ batch,
        int N, int NT,
        float* __restrict__ accb, float* __restrict__ den) {
    __shared__ __align__(16) char Xf0[32768];
    __shared__ __align__(16) char Xf1[32768];
    __shared__ __align__(16) float red[4][256];
    __shared__ float scpart[4][32];
    __shared__ int   gmin4[4];
    __shared__ float denw[4];

    const int tid = threadIdx.x;
    const int w   = tid >> 6;
    const int l   = tid & 63;
    const int l15 = l & 15;
    const int g4  = l >> 4;

    const int tpb = (NT + NBLK - 1) / NBLK;
    int t = blockIdx.x * tpb;
    const int t1 = min(NT, t + tpb);
    if (t >= t1) return;

    // cache this wave's W1p quarter (cols 64w..64w+63): 32 x bf16x8 = 128 VGPR
    bf16x8 bfr[32];
    #pragma unroll
    for (int kk = 0; kk < 8; ++kk)
        #pragma unroll
        for (int n = 0; n < 4; ++n)
            bfr[kk * 4 + n] = *reinterpret_cast<const bf16x8*>(
                W1p + (size_t)(((kk * 16) + (w * 4 + n)) * 64 + l) * 8);

    float b1v[4], w2v[4];
    #pragma unroll
    for (int n = 0; n < 4; ++n) {
        int col = 64 * w + 16 * n + l15;
        b1v[n] = b1[col];
        w2v[n] = W2[col];
    }
    (void)b2;   // b2 cancels in attn = e/(sum e); verified r11/r12 (same absmax)

    // prologue: stage first tile into Xf0
    STAGE(Xf0, t);

    float4 a4 = make_float4(0.f, 0.f, 0.f, 0.f);
    float den_p = 0.f;
    int g_cur = -1;
    int gnv = 0;
    int bg[8];   // kernel scope: final FLUSHX uses last body's values

    while (true) {
        BODY(Xf0, Xf1);
        if (t >= t1) break;
        BODY(Xf1, Xf0);
        if (t >= t1) break;
    }

    // final flush of the last graph
    FLUSHX();
}

// ---------------------------------------------------------------------------
__global__ void __launch_bounds__(256)
norm_k(const float* __restrict__ accb, const float* __restrict__ den,
       float* __restrict__ out) {
    int g = blockIdx.x;
    float dv = den[g];
    float inv = (dv > 0.f) ? 1.0f / dv : 0.f;
    out[(size_t)g * D + threadIdx.x] = accb[(size_t)g * D + threadIdx.x] * inv;
}

// ---------------------------------------------------------------------------
extern "C" void kernel_launch(void* const* d_in, const int* in_sizes, int n_in,
                              void* d_out, int out_size, void* d_ws, size_t ws_size,
                              hipStream_t stream) {
    const float* x     = (const float*)d_in[0];
    const int*   batch = (const int*)d_in[1];
    const float* W1    = (const float*)d_in[3];
    const float* b1    = (const float*)d_in[4];
    const float* W2    = (const float*)d_in[5];
    const float* b2    = (const float*)d_in[6];
    float* out = (float*)d_out;

    const int N = in_sizes[0] / D;
    const int G = out_size / D;
    const int NT = (N + ROWS - 1) / ROWS;

    char* ws = (char*)d_ws;
    unsigned short* W1p = (unsigned short*)ws;               // 128 KB
    float* accb = (float*)(ws + 131072);                     // G*D*4 bytes
    float* den  = (float*)(ws + 131072 + (size_t)G * D * 4); // G*4, contiguous

    zero_k<<<dim3((G * D + G + 255) / 256), dim3(256), 0, stream>>>(accb, G * D + G);
    pack_w1_k<<<dim3(256), dim3(256), 0, stream>>>(W1, W1p);
    fused_k<<<dim3(min(NBLK, NT)), dim3(256), 0, stream>>>(x, W1p, b1, W2, b2, batch,
                                                           N, NT, accb, den);
    norm_k<<<dim3(G), dim3(256), 0, stream>>>(accb, den, out);
}